// Round 1
// baseline (1904.132 us; speedup 1.0000x reference)
//
#include <hip/hip_runtime.h>

typedef unsigned short u16;
typedef __attribute__((ext_vector_type(8))) short short8;
typedef __attribute__((ext_vector_type(4))) float f32x4;

__device__ __forceinline__ u16 f2b(float f){
    unsigned u = __builtin_bit_cast(unsigned, f);
    u += 0x7fffu + ((u >> 16) & 1u);   // RNE
    return (u16)(u >> 16);
}
__device__ __forceinline__ float b2f(u16 s){
    unsigned u = ((unsigned)s) << 16;
    return __builtin_bit_cast(float, u);
}
__device__ __forceinline__ float sigm(float x){ return 1.f/(1.f + __expf(-x)); }
__device__ __forceinline__ float tanh_(float x){
    float e = __expf(-2.f * fabsf(x));
    float t = (1.f - e)/(1.f + e);
    return x < 0.f ? -t : t;
}

// ---------------- fp32 -> bf16 conversion ----------------
__global__ __launch_bounds__(256) void cvt_bf16(const float* __restrict__ s,
                                                u16* __restrict__ d, int n4){
    int i = blockIdx.x*256 + threadIdx.x;
    if (i < n4){
        float4 v = ((const float4*)s)[i];
        ushort4 o;
        o.x = f2b(v.x); o.y = f2b(v.y); o.z = f2b(v.z); o.w = f2b(v.w);
        ((ushort4*)d)[i] = o;
    }
}

// ---------------- embedding-gather + input projection GEMM ----------------
// pre[m, n] = sum_k E[tok[m], k] * Wt[n, k] + bias(n);  M x 1024, K=768
__global__ __launch_bounds__(256) void gemm_embed(
    const u16* __restrict__ E, const int* __restrict__ tok,
    const u16* __restrict__ Wt, const float* __restrict__ bf_,
    const float* __restrict__ bb_, u16* __restrict__ pre)
{
    __shared__ __align__(16) u16 Asm[128*32];
    __shared__ __align__(16) u16 Bsm[128*32];
    const int m0 = blockIdx.x * 128, n0 = blockIdx.y * 128;
    const int tid = threadIdx.x;
    const int ar = tid >> 2, ch = (tid & 3) * 8;
    const u16* ap0 = E + (size_t)tok[m0 + ar] * 768 + ch;
    const u16* ap1 = E + (size_t)tok[m0 + 64 + ar] * 768 + ch;
    const u16* bp0 = Wt + (size_t)(n0 + ar) * 768 + ch;
    const u16* bp1 = Wt + (size_t)(n0 + 64 + ar) * 768 + ch;
    const int lane = tid & 63, wave = tid >> 6;
    const int wm = (wave >> 1) * 64, wn = (wave & 1) * 64;
    const int qr = lane >> 4, lr = lane & 15;
    f32x4 acc[4][4] = {};
    for (int k0 = 0; k0 < 768; k0 += 32){
        __syncthreads();
        *(short8*)&Asm[ar*32 + ch]      = *(const short8*)(ap0 + k0);
        *(short8*)&Asm[(64+ar)*32 + ch] = *(const short8*)(ap1 + k0);
        *(short8*)&Bsm[ar*32 + ch]      = *(const short8*)(bp0 + k0);
        *(short8*)&Bsm[(64+ar)*32 + ch] = *(const short8*)(bp1 + k0);
        __syncthreads();
        short8 af[4], bfr[4];
        #pragma unroll
        for (int i = 0; i < 4; ++i){
            af[i]  = *(const short8*)&Asm[(wm + i*16 + lr)*32 + qr*8];
            bfr[i] = *(const short8*)&Bsm[(wn + i*16 + lr)*32 + qr*8];
        }
        #pragma unroll
        for (int i = 0; i < 4; ++i)
            #pragma unroll
            for (int j = 0; j < 4; ++j)
                acc[i][j] = __builtin_amdgcn_mfma_f32_16x16x32_bf16(af[i], bfr[j], acc[i][j], 0, 0, 0);
    }
    #pragma unroll
    for (int j = 0; j < 4; ++j){
        int col = n0 + wn + j*16 + lr;
        float bias = col < 512 ? bf_[col] : bb_[col - 512];
        #pragma unroll
        for (int i = 0; i < 4; ++i){
            #pragma unroll
            for (int r = 0; r < 4; ++r){
                int row = m0 + wm + i*16 + qr*4 + r;
                pre[(size_t)row*1024 + col] = f2b(acc[i][j][r] + bias);
            }
        }
    }
}

// ---------------- LSTM recurrent scan: one workgroup per (chain, dir) ----------------
// chains 0..63: word (T=1024);  64..1087: sent (T=64)
__global__ __launch_bounds__(512) void lstm_scan(
    const u16* __restrict__ preW, const u16* __restrict__ preS,
    const float* __restrict__ whhWf, const float* __restrict__ whhWb,
    const float* __restrict__ whhSf, const float* __restrict__ whhSb,
    float* __restrict__ fo, float* __restrict__ fs,
    u16* __restrict__ foB, u16* __restrict__ fsB)
{
    const int chain = blockIdx.x;
    const int tid = threadIdx.x;
    const u16* pre; const float* whh; float* out; u16* outB;
    int T, row0, dir;
    if (chain < 64){
        int b = chain >> 1; dir = chain & 1;
        T = 1024; row0 = b * 1024; pre = preW;
        whh = dir ? whhWb : whhWf; out = fo; outB = foB;
    } else {
        int c = chain - 64; int sb = c >> 1; dir = c & 1;
        T = 64; row0 = sb * 64; pre = preS;
        whh = dir ? whhSb : whhSf; out = fs; outB = fsB;
    }
    // W_hh row for this thread's gate -> 128 VGPRs
    float W[128];
    {
        const float4* wr = (const float4*)(whh + (size_t)tid * 128);
        #pragma unroll
        for (int k = 0; k < 32; ++k){
            float4 v = wr[k];
            W[4*k+0]=v.x; W[4*k+1]=v.y; W[4*k+2]=v.z; W[4*k+3]=v.w;
        }
    }
    __shared__ __align__(16) float h_lds[128];
    __shared__ __align__(16) float g_lds[512];
    if (tid < 128) h_lds[tid] = 0.f;
    float c_st = 0.f;
    __syncthreads();
    const int t0 = dir ? T - 1 : 0, dt = dir ? -1 : 1;
    const long base = (long)(row0 + t0) * 1024 + dir * 512 + tid;
    const long stp = (long)dt * 1024;
    u16 p0 = pre[base];
    u16 p1 = pre[base + (T > 1 ? stp : 0)];
    for (int it = 0; it < T; ++it){
        u16 p2 = (it + 2 < T) ? pre[base + stp * (it + 2)] : (u16)0;
        // g = pre + W_hh[gate,:] . h   (4 independent FMA chains)
        float ga = b2f(p0), gb2 = 0.f, gc = 0.f, gd = 0.f;
        #pragma unroll
        for (int k = 0; k < 128; k += 16){
            float4 h0 = *(const float4*)(h_lds + k);
            float4 h1 = *(const float4*)(h_lds + k + 4);
            float4 h2 = *(const float4*)(h_lds + k + 8);
            float4 h3 = *(const float4*)(h_lds + k + 12);
            ga  = fmaf(W[k+0],  h0.x, ga);  ga  = fmaf(W[k+1],  h0.y, ga);
            ga  = fmaf(W[k+2],  h0.z, ga);  ga  = fmaf(W[k+3],  h0.w, ga);
            gb2 = fmaf(W[k+4],  h1.x, gb2); gb2 = fmaf(W[k+5],  h1.y, gb2);
            gb2 = fmaf(W[k+6],  h1.z, gb2); gb2 = fmaf(W[k+7],  h1.w, gb2);
            gc  = fmaf(W[k+8],  h2.x, gc);  gc  = fmaf(W[k+9],  h2.y, gc);
            gc  = fmaf(W[k+10], h2.z, gc);  gc  = fmaf(W[k+11], h2.w, gc);
            gd  = fmaf(W[k+12], h3.x, gd);  gd  = fmaf(W[k+13], h3.y, gd);
            gd  = fmaf(W[k+14], h3.z, gd);  gd  = fmaf(W[k+15], h3.w, gd);
        }
        g_lds[tid] = (ga + gb2) + (gc + gd);
        __syncthreads();
        if (tid < 128){
            float i_s = sigm(g_lds[tid]);
            float f_s = sigm(g_lds[128 + tid]);
            float g_t = tanh_(g_lds[256 + tid]);
            float o_s = sigm(g_lds[384 + tid]);
            c_st = f_s * c_st + i_s * g_t;
            float h = o_s * tanh_(c_st);
            h_lds[tid] = h;
            int row = row0 + t0 + dt * it;
            size_t o = (size_t)row * 256 + dir * 128 + tid;
            out[o] = h;
            outB[o] = f2b(h);
        }
        __syncthreads();
        p0 = p1; p1 = p2;
    }
}

// ---------------- gate GEMM + blend epilogue ----------------
// gamma = sigmoid([fo|fs] @ gW^T + gb); out = gamma*fo + (1-gamma)*fs
__global__ __launch_bounds__(256) void gemm_gate(
    const u16* __restrict__ foB, const u16* __restrict__ fsB,
    const u16* __restrict__ gW, const float* __restrict__ gb,
    const float* __restrict__ fo, const float* __restrict__ fs,
    float* __restrict__ out)
{
    __shared__ __align__(16) u16 Asm[128*32];
    __shared__ __align__(16) u16 Bsm[128*32];
    const int m0 = blockIdx.x * 128, n0 = blockIdx.y * 128;
    const int tid = threadIdx.x;
    const int ar = tid >> 2, ch = (tid & 3) * 8;
    const u16* af0 = foB + (size_t)(m0 + ar) * 256 + ch;
    const u16* af1 = foB + (size_t)(m0 + 64 + ar) * 256 + ch;
    const u16* as0 = fsB + (size_t)(m0 + ar) * 256 + ch;
    const u16* as1 = fsB + (size_t)(m0 + 64 + ar) * 256 + ch;
    const u16* bp0 = gW + (size_t)(n0 + ar) * 512 + ch;
    const u16* bp1 = gW + (size_t)(n0 + 64 + ar) * 512 + ch;
    const int lane = tid & 63, wave = tid >> 6;
    const int wm = (wave >> 1) * 64, wn = (wave & 1) * 64;
    const int qr = lane >> 4, lr = lane & 15;
    f32x4 acc[4][4] = {};
    for (int k0 = 0; k0 < 512; k0 += 32){
        __syncthreads();
        const u16* s0 = (k0 < 256) ? (af0 + k0) : (as0 + (k0 - 256));
        const u16* s1 = (k0 < 256) ? (af1 + k0) : (as1 + (k0 - 256));
        *(short8*)&Asm[ar*32 + ch]      = *(const short8*)s0;
        *(short8*)&Asm[(64+ar)*32 + ch] = *(const short8*)s1;
        *(short8*)&Bsm[ar*32 + ch]      = *(const short8*)(bp0 + k0);
        *(short8*)&Bsm[(64+ar)*32 + ch] = *(const short8*)(bp1 + k0);
        __syncthreads();
        short8 af[4], bfr[4];
        #pragma unroll
        for (int i = 0; i < 4; ++i){
            af[i]  = *(const short8*)&Asm[(wm + i*16 + lr)*32 + qr*8];
            bfr[i] = *(const short8*)&Bsm[(wn + i*16 + lr)*32 + qr*8];
        }
        #pragma unroll
        for (int i = 0; i < 4; ++i)
            #pragma unroll
            for (int j = 0; j < 4; ++j)
                acc[i][j] = __builtin_amdgcn_mfma_f32_16x16x32_bf16(af[i], bfr[j], acc[i][j], 0, 0, 0);
    }
    #pragma unroll
    for (int j = 0; j < 4; ++j){
        int col = n0 + wn + j*16 + lr;   // 0..255
        float bias = gb[col];
        #pragma unroll
        for (int i = 0; i < 4; ++i){
            #pragma unroll
            for (int r = 0; r < 4; ++r){
                int row = m0 + wm + i*16 + qr*4 + r;
                size_t o = (size_t)row*256 + col;
                float gamma = sigm(acc[i][j][r] + bias);
                out[o] = gamma * fo[o] + (1.f - gamma) * fs[o];
            }
        }
    }
}

extern "C" void kernel_launch(void* const* d_in, const int* in_sizes, int n_in,
                              void* d_out, int out_size, void* d_ws, size_t ws_size,
                              hipStream_t stream)
{
    (void)in_sizes; (void)n_in; (void)out_size; (void)ws_size;
    const int*   wordTok = (const int*)d_in[0];
    const int*   sentTok = (const int*)d_in[1];
    const float* E       = (const float*)d_in[3];
    const float* WihWf   = (const float*)d_in[4];
    const float* WhhWf   = (const float*)d_in[5];
    const float* bWf     = (const float*)d_in[6];
    const float* WihWb   = (const float*)d_in[7];
    const float* WhhWb   = (const float*)d_in[8];
    const float* bWb     = (const float*)d_in[9];
    const float* WihSf   = (const float*)d_in[10];
    const float* WhhSf   = (const float*)d_in[11];
    const float* bSf     = (const float*)d_in[12];
    const float* WihSb   = (const float*)d_in[13];
    const float* WhhSb   = (const float*)d_in[14];
    const float* bSb     = (const float*)d_in[15];
    const float* gateW   = (const float*)d_in[16];
    const float* gateB   = (const float*)d_in[17];
    float* out = (float*)d_out;

    char* w = (char*)d_ws;
    u16* Eb   = (u16*)w;  w += (size_t)30522*768*2;
    u16* Ww   = (u16*)w;  w += (size_t)1024*768*2;
    u16* Ws_  = (u16*)w;  w += (size_t)1024*768*2;
    u16* gWb  = (u16*)w;  w += (size_t)256*512*2;
    u16* preW = (u16*)w;  w += (size_t)32768*1024*2;
    u16* preS = (u16*)w;  w += (size_t)32768*1024*2;
    float* fo = (float*)w; w += (size_t)32768*256*4;
    float* fs = (float*)w; w += (size_t)32768*256*4;
    u16* foB  = (u16*)w;  w += (size_t)32768*256*2;
    u16* fsB  = (u16*)w;  w += (size_t)32768*256*2;

    const int nE4 = 30522*768/4;
    cvt_bf16<<<(nE4+255)/256, 256, 0, stream>>>(E, Eb, nE4);
    const int nW4 = 512*768/4;
    cvt_bf16<<<(nW4+255)/256, 256, 0, stream>>>(WihWf, Ww, nW4);
    cvt_bf16<<<(nW4+255)/256, 256, 0, stream>>>(WihWb, Ww + 512*768, nW4);
    cvt_bf16<<<(nW4+255)/256, 256, 0, stream>>>(WihSf, Ws_, nW4);
    cvt_bf16<<<(nW4+255)/256, 256, 0, stream>>>(WihSb, Ws_ + 512*768, nW4);
    const int nG4 = 256*512/4;
    cvt_bf16<<<(nG4+255)/256, 256, 0, stream>>>(gateW, gWb, nG4);

    gemm_embed<<<dim3(256,8), 256, 0, stream>>>(Eb, wordTok, Ww, bWf, bWb, preW);
    gemm_embed<<<dim3(256,8), 256, 0, stream>>>(Eb, sentTok, Ws_, bSf, bSb, preS);
    lstm_scan<<<1088, 512, 0, stream>>>(preW, preS, WhhWf, WhhWb, WhhSf, WhhSb,
                                        fo, fs, foB, fsB);
    gemm_gate<<<dim3(256,2), 256, 0, stream>>>(foB, fsB, gWb, gateB, fo, fs, out);
}

// Round 2
// 1739.655 us; speedup vs baseline: 1.0945x; 1.0945x over previous
//
#include <hip/hip_runtime.h>

typedef unsigned short u16;
typedef __attribute__((ext_vector_type(8))) short short8;
typedef __attribute__((ext_vector_type(4))) float f32x4;

__device__ __forceinline__ u16 f2b(float f){
    unsigned u = __builtin_bit_cast(unsigned, f);
    u += 0x7fffu + ((u >> 16) & 1u);   // RNE
    return (u16)(u >> 16);
}
__device__ __forceinline__ float b2f(u16 s){
    unsigned u = ((unsigned)s) << 16;
    return __builtin_bit_cast(float, u);
}
__device__ __forceinline__ float sigm(float x){ return 1.f/(1.f + __expf(-x)); }
__device__ __forceinline__ float tanh_(float x){
    float e = __expf(-2.f * fabsf(x));
    float t = (1.f - e)/(1.f + e);
    return x < 0.f ? -t : t;
}
__device__ __forceinline__ float quad_bcast(float v, int k){
    // dst lane L gets src lane (L & ~3) | k  (BitMode: and=0x1C, or=k, xor=0)
    int b = __builtin_bit_cast(int, v);
    int r;
    switch (k){
        case 0: r = __builtin_amdgcn_ds_swizzle(b, 0x001C); break;
        case 1: r = __builtin_amdgcn_ds_swizzle(b, 0x003C); break;
        case 2: r = __builtin_amdgcn_ds_swizzle(b, 0x005C); break;
        default:r = __builtin_amdgcn_ds_swizzle(b, 0x007C); break;
    }
    return __builtin_bit_cast(float, r);
}

// ---------------- fp32 -> bf16 conversion ----------------
__global__ __launch_bounds__(256) void cvt_bf16(const float* __restrict__ s,
                                                u16* __restrict__ d, int n4){
    int i = blockIdx.x*256 + threadIdx.x;
    if (i < n4){
        float4 v = ((const float4*)s)[i];
        ushort4 o;
        o.x = f2b(v.x); o.y = f2b(v.y); o.z = f2b(v.z); o.w = f2b(v.w);
        ((ushort4*)d)[i] = o;
    }
}

// ---- W_ih cvt with row permutation: out row (unit*4+gate) = in row (gate*128+unit) ----
__global__ __launch_bounds__(192) void cvt_wih_perm(const float* __restrict__ s,
                                                    u16* __restrict__ d){
    int r = blockIdx.x;               // 0..511 input row
    int j = threadIdx.x;              // 0..191 float4 within row
    int g = r >> 7, u = r & 127;
    int ro = u * 4 + g;
    float4 v = ((const float4*)(s + (size_t)r * 768))[j];
    ushort4 o;
    o.x = f2b(v.x); o.y = f2b(v.y); o.z = f2b(v.z); o.w = f2b(v.w);
    ((ushort4*)(d + (size_t)ro * 768))[j] = o;
}

// ---------------- embedding-gather + input projection GEMM ----------------
// pre[m, n] = sum_k E[tok[m], k] * Wt[n, k] + bias(n);  M x 1024, K=768
// Wt rows (and hence pre cols) are PERMUTED: within each 512-half, p = unit*4+gate.
__global__ __launch_bounds__(256) void gemm_embed(
    const u16* __restrict__ E, const int* __restrict__ tok,
    const u16* __restrict__ Wt, const float* __restrict__ bf_,
    const float* __restrict__ bb_, u16* __restrict__ pre)
{
    __shared__ __align__(16) u16 Asm[128*32];
    __shared__ __align__(16) u16 Bsm[128*32];
    const int m0 = blockIdx.x * 128, n0 = blockIdx.y * 128;
    const int tid = threadIdx.x;
    const int ar = tid >> 2, ch = (tid & 3) * 8;
    const u16* ap0 = E + (size_t)tok[m0 + ar] * 768 + ch;
    const u16* ap1 = E + (size_t)tok[m0 + 64 + ar] * 768 + ch;
    const u16* bp0 = Wt + (size_t)(n0 + ar) * 768 + ch;
    const u16* bp1 = Wt + (size_t)(n0 + 64 + ar) * 768 + ch;
    const int lane = tid & 63, wave = tid >> 6;
    const int wm = (wave >> 1) * 64, wn = (wave & 1) * 64;
    const int qr = lane >> 4, lr = lane & 15;
    f32x4 acc[4][4] = {};
    for (int k0 = 0; k0 < 768; k0 += 32){
        __syncthreads();
        *(short8*)&Asm[ar*32 + ch]      = *(const short8*)(ap0 + k0);
        *(short8*)&Asm[(64+ar)*32 + ch] = *(const short8*)(ap1 + k0);
        *(short8*)&Bsm[ar*32 + ch]      = *(const short8*)(bp0 + k0);
        *(short8*)&Bsm[(64+ar)*32 + ch] = *(const short8*)(bp1 + k0);
        __syncthreads();
        short8 af[4], bfr[4];
        #pragma unroll
        for (int i = 0; i < 4; ++i){
            af[i]  = *(const short8*)&Asm[(wm + i*16 + lr)*32 + qr*8];
            bfr[i] = *(const short8*)&Bsm[(wn + i*16 + lr)*32 + qr*8];
        }
        #pragma unroll
        for (int i = 0; i < 4; ++i)
            #pragma unroll
            for (int j = 0; j < 4; ++j)
                acc[i][j] = __builtin_amdgcn_mfma_f32_16x16x32_bf16(af[i], bfr[j], acc[i][j], 0, 0, 0);
    }
    #pragma unroll
    for (int j = 0; j < 4; ++j){
        int col = n0 + wn + j*16 + lr;
        int d = col >> 9, p = col & 511;
        int uu = p >> 2, gg = p & 3;
        float bias = (d ? bb_ : bf_)[gg*128 + uu];
        #pragma unroll
        for (int i = 0; i < 4; ++i){
            #pragma unroll
            for (int r = 0; r < 4; ++r){
                int row = m0 + wm + i*16 + qr*4 + r;
                pre[(size_t)row*1024 + col] = f2b(acc[i][j][r] + bias);
            }
        }
    }
}

// ---------------- LSTM recurrent scan: one workgroup per (chain, dir) ----------------
// chains 0..63: word (T=1024);  64..1087: sent (T=64)
// Thread tid = unit*4 + gate (unit = tid>>2, gate = tid&3).
__global__ __launch_bounds__(512, 2) void lstm_scan(
    const u16* __restrict__ preW, const u16* __restrict__ preS,
    const float* __restrict__ whhWf, const float* __restrict__ whhWb,
    const float* __restrict__ whhSf, const float* __restrict__ whhSb,
    float* __restrict__ fo, float* __restrict__ fs,
    u16* __restrict__ foB, u16* __restrict__ fsB)
{
    const int chain = blockIdx.x;
    const int tid = threadIdx.x;
    const u16* pre; const float* whh; float* out; u16* outB;
    int T, row0, dir;
    if (chain < 64){
        int b = chain >> 1; dir = chain & 1;
        T = 1024; row0 = b * 1024; pre = preW;
        whh = dir ? whhWb : whhWf; out = fo; outB = foB;
    } else {
        int c = chain - 64; int sb = c >> 1; dir = c & 1;
        T = 64; row0 = sb * 64; pre = preS;
        whh = dir ? whhSb : whhSf; out = fs; outB = fsB;
    }
    const int u = tid >> 2, g = tid & 3;
    // W_hh row (gate*128 + unit) for this thread -> 128 VGPRs (256-VGPR cap via launch_bounds)
    float W[128];
    {
        const float4* wr = (const float4*)(whh + (size_t)(g*128 + u) * 128);
        #pragma unroll
        for (int k = 0; k < 32; ++k){
            float4 v = wr[k];
            W[4*k+0]=v.x; W[4*k+1]=v.y; W[4*k+2]=v.z; W[4*k+3]=v.w;
        }
    }
    __shared__ __align__(16) float h_lds[2][128];
    __shared__ __align__(16) float h_hist[32][128];
    if (tid < 128) h_lds[0][tid] = 0.f;
    float c_st = 0.f;
    __syncthreads();
    const int t0 = dir ? T - 1 : 0, dt = dir ? -1 : 1;
    const long base = (long)(row0 + t0) * 1024 + dir * 512 + tid;
    const long stp = (long)dt * 1024;

    for (int it8 = 0; it8 < T; it8 += 8){
        // batch-load 8 steps of pre into registers: ONE vmcnt drain per 8 steps
        u16 pb[8];
        const u16* pp = pre + base + stp * it8;
        #pragma unroll
        for (int j = 0; j < 8; ++j) pb[j] = pp[stp * j];

        #pragma unroll
        for (int s = 0; s < 8; ++s){
            const float* hb = &h_lds[s & 1][0];
            float* hw = &h_lds[(s + 1) & 1][0];
            float a0 = b2f(pb[s]), a1 = 0.f, a2 = 0.f, a3 = 0.f;
            #pragma unroll
            for (int k = 0; k < 128; k += 16){
                float4 h0 = *(const float4*)(hb + k);
                float4 h1 = *(const float4*)(hb + k + 4);
                float4 h2 = *(const float4*)(hb + k + 8);
                float4 h3 = *(const float4*)(hb + k + 12);
                a0 = fmaf(W[k+0],  h0.x, a0); a0 = fmaf(W[k+1],  h0.y, a0);
                a0 = fmaf(W[k+2],  h0.z, a0); a0 = fmaf(W[k+3],  h0.w, a0);
                a1 = fmaf(W[k+4],  h1.x, a1); a1 = fmaf(W[k+5],  h1.y, a1);
                a1 = fmaf(W[k+6],  h1.z, a1); a1 = fmaf(W[k+7],  h1.w, a1);
                a2 = fmaf(W[k+8],  h2.x, a2); a2 = fmaf(W[k+9],  h2.y, a2);
                a2 = fmaf(W[k+10], h2.z, a2); a2 = fmaf(W[k+11], h2.w, a2);
                a3 = fmaf(W[k+12], h3.x, a3); a3 = fmaf(W[k+13], h3.y, a3);
                a3 = fmaf(W[k+14], h3.z, a3); a3 = fmaf(W[k+15], h3.w, a3);
            }
            float gv = (a0 + a1) + (a2 + a3);
            // gather the quad's 4 gate values (i,f,g,o) into every lane
            float vi = quad_bcast(gv, 0);
            float vf = quad_bcast(gv, 1);
            float vg = quad_bcast(gv, 2);
            float vo = quad_bcast(gv, 3);
            c_st = sigm(vf) * c_st + sigm(vi) * tanh_(vg);
            float h = sigm(vo) * tanh_(c_st);
            if (g == 0){
                hw[u] = h;
                h_hist[(it8 + s) & 31][u] = h;
            }
            __syncthreads();
        }
        // flush 32 completed steps with coalesced vector stores
        if ((it8 & 31) == 24){
            int sBase = it8 - 24;
            int sF = tid >> 4;            // 0..31
            int uF = (tid & 15) * 8;      // 0..120
            int itF = sBase + sF;
            int row = row0 + t0 + dt * itF;
            size_t o = (size_t)row * 256 + dir * 128 + uF;
            float4 a = *(const float4*)&h_hist[sF][uF];
            float4 b4 = *(const float4*)&h_hist[sF][uF + 4];
            *(float4*)(out + o) = a;
            *(float4*)(out + o + 4) = b4;
            ushort4 c0; c0.x = f2b(a.x);  c0.y = f2b(a.y);  c0.z = f2b(a.z);  c0.w = f2b(a.w);
            ushort4 c1; c1.x = f2b(b4.x); c1.y = f2b(b4.y); c1.z = f2b(b4.z); c1.w = f2b(b4.w);
            *(ushort4*)(outB + o) = c0;
            *(ushort4*)(outB + o + 4) = c1;
            __syncthreads();
        }
    }
}

// ---------------- gate GEMM + blend epilogue ----------------
// gamma = sigmoid([fo|fs] @ gW^T + gb); out = gamma*fo + (1-gamma)*fs
__global__ __launch_bounds__(256) void gemm_gate(
    const u16* __restrict__ foB, const u16* __restrict__ fsB,
    const u16* __restrict__ gW, const float* __restrict__ gb,
    const float* __restrict__ fo, const float* __restrict__ fs,
    float* __restrict__ out)
{
    __shared__ __align__(16) u16 Asm[128*32];
    __shared__ __align__(16) u16 Bsm[128*32];
    const int m0 = blockIdx.x * 128, n0 = blockIdx.y * 128;
    const int tid = threadIdx.x;
    const int ar = tid >> 2, ch = (tid & 3) * 8;
    const u16* af0 = foB + (size_t)(m0 + ar) * 256 + ch;
    const u16* af1 = foB + (size_t)(m0 + 64 + ar) * 256 + ch;
    const u16* as0 = fsB + (size_t)(m0 + ar) * 256 + ch;
    const u16* as1 = fsB + (size_t)(m0 + 64 + ar) * 256 + ch;
    const u16* bp0 = gW + (size_t)(n0 + ar) * 512 + ch;
    const u16* bp1 = gW + (size_t)(n0 + 64 + ar) * 512 + ch;
    const int lane = tid & 63, wave = tid >> 6;
    const int wm = (wave >> 1) * 64, wn = (wave & 1) * 64;
    const int qr = lane >> 4, lr = lane & 15;
    f32x4 acc[4][4] = {};
    for (int k0 = 0; k0 < 512; k0 += 32){
        __syncthreads();
        const u16* s0 = (k0 < 256) ? (af0 + k0) : (as0 + (k0 - 256));
        const u16* s1 = (k0 < 256) ? (af1 + k0) : (as1 + (k0 - 256));
        *(short8*)&Asm[ar*32 + ch]      = *(const short8*)s0;
        *(short8*)&Asm[(64+ar)*32 + ch] = *(const short8*)s1;
        *(short8*)&Bsm[ar*32 + ch]      = *(const short8*)(bp0 + k0);
        *(short8*)&Bsm[(64+ar)*32 + ch] = *(const short8*)(bp1 + k0);
        __syncthreads();
        short8 af[4], bfr[4];
        #pragma unroll
        for (int i = 0; i < 4; ++i){
            af[i]  = *(const short8*)&Asm[(wm + i*16 + lr)*32 + qr*8];
            bfr[i] = *(const short8*)&Bsm[(wn + i*16 + lr)*32 + qr*8];
        }
        #pragma unroll
        for (int i = 0; i < 4; ++i)
            #pragma unroll
            for (int j = 0; j < 4; ++j)
                acc[i][j] = __builtin_amdgcn_mfma_f32_16x16x32_bf16(af[i], bfr[j], acc[i][j], 0, 0, 0);
    }
    #pragma unroll
    for (int j = 0; j < 4; ++j){
        int col = n0 + wn + j*16 + lr;   // 0..255
        float bias = gb[col];
        #pragma unroll
        for (int i = 0; i < 4; ++i){
            #pragma unroll
            for (int r = 0; r < 4; ++r){
                int row = m0 + wm + i*16 + qr*4 + r;
                size_t o = (size_t)row*256 + col;
                float gamma = sigm(acc[i][j][r] + bias);
                out[o] = gamma * fo[o] + (1.f - gamma) * fs[o];
            }
        }
    }
}

extern "C" void kernel_launch(void* const* d_in, const int* in_sizes, int n_in,
                              void* d_out, int out_size, void* d_ws, size_t ws_size,
                              hipStream_t stream)
{
    (void)in_sizes; (void)n_in; (void)out_size; (void)ws_size;
    const int*   wordTok = (const int*)d_in[0];
    const int*   sentTok = (const int*)d_in[1];
    const float* E       = (const float*)d_in[3];
    const float* WihWf   = (const float*)d_in[4];
    const float* WhhWf   = (const float*)d_in[5];
    const float* bWf     = (const float*)d_in[6];
    const float* WihWb   = (const float*)d_in[7];
    const float* WhhWb   = (const float*)d_in[8];
    const float* bWb     = (const float*)d_in[9];
    const float* WihSf   = (const float*)d_in[10];
    const float* WhhSf   = (const float*)d_in[11];
    const float* bSf     = (const float*)d_in[12];
    const float* WihSb   = (const float*)d_in[13];
    const float* WhhSb   = (const float*)d_in[14];
    const float* bSb     = (const float*)d_in[15];
    const float* gateW   = (const float*)d_in[16];
    const float* gateB   = (const float*)d_in[17];
    float* out = (float*)d_out;

    char* w = (char*)d_ws;
    u16* Eb   = (u16*)w;  w += (size_t)30522*768*2;
    u16* Ww   = (u16*)w;  w += (size_t)1024*768*2;
    u16* Ws_  = (u16*)w;  w += (size_t)1024*768*2;
    u16* gWb  = (u16*)w;  w += (size_t)256*512*2;
    u16* preW = (u16*)w;  w += (size_t)32768*1024*2;
    u16* preS = (u16*)w;  w += (size_t)32768*1024*2;
    float* fo = (float*)w; w += (size_t)32768*256*4;
    float* fs = (float*)w; w += (size_t)32768*256*4;
    u16* foB  = (u16*)w;  w += (size_t)32768*256*2;
    u16* fsB  = (u16*)w;  w += (size_t)32768*256*2;

    const int nE4 = 30522*768/4;
    cvt_bf16<<<(nE4+255)/256, 256, 0, stream>>>(E, Eb, nE4);
    cvt_wih_perm<<<512, 192, 0, stream>>>(WihWf, Ww);
    cvt_wih_perm<<<512, 192, 0, stream>>>(WihWb, Ww + 512*768);
    cvt_wih_perm<<<512, 192, 0, stream>>>(WihSf, Ws_);
    cvt_wih_perm<<<512, 192, 0, stream>>>(WihSb, Ws_ + 512*768);
    const int nG4 = 256*512/4;
    cvt_bf16<<<(nG4+255)/256, 256, 0, stream>>>(gateW, gWb, nG4);

    gemm_embed<<<dim3(256,8), 256, 0, stream>>>(Eb, wordTok, Ww, bWf, bWb, preW);
    gemm_embed<<<dim3(256,8), 256, 0, stream>>>(Eb, sentTok, Ws_, bSf, bSb, preS);
    lstm_scan<<<1088, 512, 0, stream>>>(preW, preS, WhhWf, WhhWb, WhhSf, WhhSb,
                                        fo, fs, foB, fsB);
    gemm_gate<<<dim3(256,2), 256, 0, stream>>>(foB, fsB, gWb, gateB, fo, fs, out);
}